// Round 3
// baseline (1606.101 us; speedup 1.0000x reference)
//
#include <hip/hip_runtime.h>
#include <hip/hip_bf16.h>

typedef __attribute__((ext_vector_type(8))) short short8;
typedef __attribute__((ext_vector_type(4))) float f32x4;

#define MFMA_BF16(a, b, c) __builtin_amdgcn_mfma_f32_16x16x32_bf16((a), (b), (c), 0, 0, 0)
#define GLDS16(g, l)                                                                        \
  __builtin_amdgcn_global_load_lds((const __attribute__((address_space(1))) void*)(g),      \
                                   (__attribute__((address_space(3))) void*)(l), 16, 0, 0)
#define SBAR() __builtin_amdgcn_s_barrier()
#define SCHED0() __builtin_amdgcn_sched_barrier(0)

static constexpr int NTOK = 4096;
static constexpr int DDIM = 4096;
static constexpr int FDIM = 11008;

// ---------------------------------------------------------------- utilities

__device__ __forceinline__ float wave_max64(float m) {
#pragma unroll
  for (int o = 32; o > 0; o >>= 1) m = fmaxf(m, __shfl_xor(m, o));
  return m;
}

__global__ void zero_slots(unsigned* s) {
  if (threadIdx.x < 16) s[threadIdx.x] = 0u;
}

__global__ void absmax_kernel(const float* __restrict__ p, int n4, unsigned* __restrict__ slot) {
  float m = 0.f;
  const int stride = gridDim.x * blockDim.x;
  for (int i = blockIdx.x * blockDim.x + threadIdx.x; i < n4; i += stride) {
    float4 v = reinterpret_cast<const float4*>(p)[i];
    m = fmaxf(fmaxf(fabsf(v.x), fabsf(v.y)), fmaxf(fmaxf(fabsf(v.z), fabsf(v.w)), m));
  }
  m = wave_max64(m);
  __shared__ float wm[4];
  const int lane = threadIdx.x & 63, w = threadIdx.x >> 6;
  if (lane == 0) wm[w] = m;
  __syncthreads();
  if (threadIdx.x == 0) {
    m = fmaxf(fmaxf(wm[0], wm[1]), fmaxf(wm[2], wm[3]));
    atomicMax(slot, __float_as_uint(m));
  }
}

// q = rint(t / s), stored as bf16 (exact: |q| <= 127 < 256)
__global__ void quant_kernel(const float* __restrict__ in, unsigned short* __restrict__ out,
                             int n4, const unsigned* __restrict__ slot) {
  const float s = fmaxf(__uint_as_float(*slot), 1e-8f) / 127.0f;
  const int stride = gridDim.x * blockDim.x;
  for (int i = blockIdx.x * blockDim.x + threadIdx.x; i < n4; i += stride) {
    float4 v = reinterpret_cast<const float4*>(in)[i];
    ushort4 o;
    o.x = (unsigned short)(__float_as_uint(rintf(v.x / s)) >> 16);
    o.y = (unsigned short)(__float_as_uint(rintf(v.y / s)) >> 16);
    o.z = (unsigned short)(__float_as_uint(rintf(v.z / s)) >> 16);
    o.w = (unsigned short)(__float_as_uint(rintf(v.w / s)) >> 16);
    reinterpret_cast<ushort4*>(out)[i] = o;
  }
}

// ----------------------------------------------- 256x256 8-phase GEMM (bf16)
// C[M][N] = scale * A[M][K] . B[N][K]^T, A/B integer-valued bf16 (as ushort).
// 8 waves (2Mx4N), per-wave C = 128x64. BK=64, double-buffered 128 KiB LDS.
// LDS per buffer (shorts): A[256][64] @0, B[256][64] @16384.
// XOR swizzle: 16B-granule g_phys = g_logical ^ (row & 7), applied on the
// global SOURCE address (linear LDS dest) and on ds_read (both-sides rule).
// Schedule (2 tiles ahead): during tile kt (buf b = kt&1) stage tile kt+2
// into the SAME buffer b: ph3 stages A halves (A region register-consumed
// after ph2's barrier), ph4 stages B halves (B free after ph3's barrier).
// Boundary: vmcnt(8) (16 outstanding -> keep newest 8 = tile kt+1's) ->
// every load gets ~6 phases (~900+ cyc) of cover.
// XCD chunking: column-major chunks so each XCD re-reads only its B panels.
// MODE 0: C = silu(v)   MODE 1: C = v * SG (in-place ok) + absmax->hslot
// MODE 2: C = v
template <int MODE>
__global__ __launch_bounds__(512, 2) void gemm8p(
    const unsigned short* __restrict__ Aq, const unsigned short* __restrict__ Bq,
    float* C, const float* SG, const unsigned* __restrict__ slots, int sA, int sB,
    unsigned* hslot, int K, int ldc) {
  __shared__ short lds[65536];  // 128 KiB

  const int t = threadIdx.x;
  const int l = t & 63;
  const int w = t >> 6;   // wave 0..7
  const int wm = w >> 2;  // 0..1
  const int wn = w & 3;   // 0..3

  // XCD-aware COLUMN-MAJOR chunking (nwg % 8 == 0 for all our grids).
  // HW block i lands on XCD i%8; give XCD k a contiguous column-major chunk.
  const int gx = gridDim.x;  // column tiles
  const int gy = gridDim.y;  // row tiles
  const int nwg = gx * gy;
  const int i0 = blockIdx.y * gx + blockIdx.x;
  const int cid = (i0 & 7) * (nwg >> 3) + (i0 >> 3);  // column-major tile idx
  const int rowA0 = (cid % gy) << 8;                  // C-row tile base
  const int colB0 = (cid / gy) << 8;                  // C-col (B-row) base

  // staging: per-thread global element offsets (instr covers 64 rows)
  const int rl = t >> 3;               // local row 0..63
  const int c16 = (t & 7) ^ (rl & 7);  // pre-swizzled 16B-granule
  const size_t aOff0 = (size_t)(rowA0 + rl) * K + c16 * 8;
  const size_t aOff1 = aOff0 + (size_t)64 * K;
  const size_t bOff0 = (size_t)(colB0 + rl) * K + c16 * 8;
  const size_t bOff1 = bOff0 + (size_t)64 * K;
  const size_t hstep = (size_t)128 * K;  // half-tile row step
  const int stW = w * 512;               // wave-uniform LDS short offset

#define STAGE2(PTR, O0, O1, LB)             \
  do {                                      \
    GLDS16((PTR) + (O0), &lds[(LB) + stW]); \
    GLDS16((PTR) + (O1), &lds[(LB) + 4096 + stW]); \
  } while (0)

#define LDA(BUF, ROW, C16) \
  (*reinterpret_cast<const short8*>(&lds[(BUF)*32768 + (ROW)*64 + (((C16) ^ ((ROW)&7)) << 3)]))
#define LDB(BUF, ROW, C16) \
  (*reinterpret_cast<const short8*>(&lds[(BUF)*32768 + 16384 + (ROW)*64 + (((C16) ^ ((ROW)&7)) << 3)]))

#define MFMA16(MH, NH, AF, BF)                                                  \
  do {                                                                          \
    _Pragma("unroll") for (int kk = 0; kk < 2; ++kk)                            \
    _Pragma("unroll") for (int m = 0; m < 4; ++m)                               \
    _Pragma("unroll") for (int n = 0; n < 2; ++n)                               \
      acc[(MH)*4 + m][(NH)*2 + n] =                                             \
          MFMA_BF16(AF[kk][m], BF[kk][n], acc[(MH)*4 + m][(NH)*2 + n]);         \
  } while (0)

  f32x4 acc[8][4];
#pragma unroll
  for (int mi = 0; mi < 8; ++mi)
#pragma unroll
    for (int ni = 0; ni < 4; ++ni) acc[mi][ni] = (f32x4){0.f, 0.f, 0.f, 0.f};

  const int NT = K >> 6;
  const int ar = wm * 128 + (l & 15);  // A row base (mh=0)
  const int br = wn * 64 + (l & 15);   // B row base (nh=0)
  const int cr = l >> 4;               // logical granule base (kk adds 4)

  // prologue: tile0 -> buf0, tile1 -> buf1 (8 loads each)
  STAGE2(Aq, aOff0, aOff1, 0);
  STAGE2(Aq, aOff0 + hstep, aOff1 + hstep, 8192);
  STAGE2(Bq, bOff0, bOff1, 16384);
  STAGE2(Bq, bOff0 + hstep, bOff1 + hstep, 24576);
  STAGE2(Aq, aOff0 + 64, aOff1 + 64, 32768);
  STAGE2(Aq, aOff0 + hstep + 64, aOff1 + hstep + 64, 32768 + 8192);
  STAGE2(Bq, bOff0 + 64, bOff1 + 64, 32768 + 16384);
  STAGE2(Bq, bOff0 + hstep + 64, bOff1 + hstep + 64, 32768 + 24576);

  for (int kt = 0; kt < NT; ++kt) {
    const int b = kt & 1;
    const size_t kO2 = (size_t)(kt + 2) * 64;  // tile+2 col offset
    const bool pf = (kt + 2 < NT);

    // ---- tile boundary: tile kt fully landed; tile kt+1's 8 stay in flight
    SCHED0();
    if (kt + 1 < NT) {
      asm volatile("s_waitcnt vmcnt(8)" ::: "memory");
    } else {
      asm volatile("s_waitcnt vmcnt(0)" ::: "memory");
    }
    SBAR();
    SCHED0();

    short8 aH[2][4], aC[2][4], b0[2][2], b1[2][2];

    // ---- phase 1: read A(mh0)+B(nh0)
#pragma unroll
    for (int kk = 0; kk < 2; ++kk)
#pragma unroll
      for (int m = 0; m < 4; ++m) aH[kk][m] = LDA(b, ar + m * 16, kk * 4 + cr);
#pragma unroll
    for (int kk = 0; kk < 2; ++kk)
#pragma unroll
      for (int n = 0; n < 2; ++n) b0[kk][n] = LDB(b, br + n * 16, kk * 4 + cr);
    SCHED0(); SBAR(); SCHED0();
    __builtin_amdgcn_s_setprio(1);
    MFMA16(0, 0, aH, b0);
    __builtin_amdgcn_s_setprio(0);
    SCHED0(); SBAR(); SCHED0();

    // ---- phase 2: read A(mh1)
#pragma unroll
    for (int kk = 0; kk < 2; ++kk)
#pragma unroll
      for (int m = 0; m < 4; ++m) aC[kk][m] = LDA(b, ar + 64 + m * 16, kk * 4 + cr);
    SCHED0(); SBAR(); SCHED0();
    __builtin_amdgcn_s_setprio(1);
    MFMA16(1, 0, aC, b0);
    __builtin_amdgcn_s_setprio(0);
    SCHED0(); SBAR(); SCHED0();

    // ---- phase 3: read B(nh1); stage (kt+2) A halves -> buf b (A free)
#pragma unroll
    for (int kk = 0; kk < 2; ++kk)
#pragma unroll
      for (int n = 0; n < 2; ++n) b1[kk][n] = LDB(b, br + 32 + n * 16, kk * 4 + cr);
    if (pf) {
      STAGE2(Aq, aOff0 + kO2, aOff1 + kO2, b * 32768);
      STAGE2(Aq, aOff0 + hstep + kO2, aOff1 + hstep + kO2, b * 32768 + 8192);
    }
    SCHED0(); SBAR(); SCHED0();
    __builtin_amdgcn_s_setprio(1);
    MFMA16(1, 1, aC, b1);
    __builtin_amdgcn_s_setprio(0);
    SCHED0(); SBAR(); SCHED0();

    // ---- phase 4: stage (kt+2) B halves -> buf b (B free after ph3)
    if (pf) {
      STAGE2(Bq, bOff0 + kO2, bOff1 + kO2, b * 32768 + 16384);
      STAGE2(Bq, bOff0 + hstep + kO2, bOff1 + hstep + kO2, b * 32768 + 24576);
    }
    SCHED0(); SBAR(); SCHED0();
    __builtin_amdgcn_s_setprio(1);
    MFMA16(0, 1, aH, b1);
    __builtin_amdgcn_s_setprio(0);
    SCHED0(); SBAR(); SCHED0();
  }

  // ------------------------------------------------------------- epilogue
  const float sa = fmaxf(__uint_as_float(slots[sA]), 1e-8f) / 127.0f;
  const float sb = fmaxf(__uint_as_float(slots[sB]), 1e-8f) / 127.0f;
  const float s = sa * sb;
  const int crow0 = rowA0 + wm * 128 + ((l >> 4) << 2);
  const int ccol0 = colB0 + wn * 64 + (l & 15);
  float hmax = 0.f;
#pragma unroll
  for (int mi = 0; mi < 8; ++mi)
#pragma unroll
    for (int ni = 0; ni < 4; ++ni)
#pragma unroll
      for (int j = 0; j < 4; ++j) {
        const int row = crow0 + (mi >> 2) * 64 + (mi & 3) * 16 + j;
        const int col = ccol0 + (ni >> 1) * 32 + (ni & 1) * 16;
        const float v = acc[mi][ni][j] * s;
        if constexpr (MODE == 0) {
          C[(size_t)row * ldc + col] = v / (1.f + expf(-v));  // silu
        } else if constexpr (MODE == 1) {
          const float h = v * SG[(size_t)row * ldc + col];
          C[(size_t)row * ldc + col] = h;
          hmax = fmaxf(hmax, fabsf(h));
        } else {
          C[(size_t)row * ldc + col] = v;
        }
      }
  if constexpr (MODE == 1) {
    hmax = wave_max64(hmax);
    if (l == 0) atomicMax(hslot, __float_as_uint(hmax));
  }
#undef STAGE2
#undef LDA
#undef LDB
#undef MFMA16
}

// ------------------------------------------------------------------- launch

extern "C" void kernel_launch(void* const* d_in, const int* in_sizes, int n_in,
                              void* d_out, int out_size, void* d_ws, size_t ws_size,
                              hipStream_t stream) {
  const float* x = (const float*)d_in[0];
  const float* w1 = (const float*)d_in[1];
  const float* w3 = (const float*)d_in[2];
  const float* w2 = (const float*)d_in[3];
  float* out = (float*)d_out;
  char* ws = (char*)d_ws;

  unsigned* slots = (unsigned*)ws;  // [0]=x [1]=w1 [2]=w3 [3]=w2 [4]=h absmax
  size_t off = 256;
  unsigned short* qx = (unsigned short*)(ws + off);
  off += (size_t)NTOK * DDIM * 2;
  unsigned short* qw3 = (unsigned short*)(ws + off);
  off += (size_t)FDIM * DDIM * 2;
  unsigned short* qw1 = (unsigned short*)(ws + off);
  off += (size_t)FDIM * DDIM * 2;
  unsigned short* qw2 = (unsigned short*)(ws + off);
  off += (size_t)FDIM * DDIM * 2;
  float* SGH = (float*)(ws + off);  // silu(gate), overwritten in-place by h
  off += (size_t)NTOK * FDIM * 4;
  unsigned short* qh = (unsigned short*)(ws + off);
  off += (size_t)NTOK * FDIM * 2;  // ~575 MB total

  const int n4x = NTOK * DDIM / 4;
  const int n4w = FDIM * DDIM / 4;
  const int n4h = NTOK * FDIM / 4;

  zero_slots<<<1, 64, 0, stream>>>(slots);
  absmax_kernel<<<2048, 256, 0, stream>>>(x, n4x, slots + 0);
  absmax_kernel<<<2048, 256, 0, stream>>>(w1, n4w, slots + 1);
  absmax_kernel<<<2048, 256, 0, stream>>>(w3, n4w, slots + 2);
  absmax_kernel<<<2048, 256, 0, stream>>>(w2, n4w, slots + 3);

  quant_kernel<<<2048, 256, 0, stream>>>(x, qx, n4x, slots + 0);
  quant_kernel<<<2048, 256, 0, stream>>>(w1, qw1, n4w, slots + 1);
  quant_kernel<<<2048, 256, 0, stream>>>(w3, qw3, n4w, slots + 2);
  quant_kernel<<<2048, 256, 0, stream>>>(w2, qw2, n4w, slots + 3);

  const dim3 gUp(FDIM / 256, NTOK / 256);  // 43 x 16 = 688 wgs
  const dim3 gDn(DDIM / 256, NTOK / 256);  // 16 x 16 = 256 wgs
  // gate: SG = silu(x.w3^T * s)
  gemm8p<0><<<gUp, 512, 0, stream>>>(qx, qw3, SGH, nullptr, slots, 0, 2, nullptr, DDIM, FDIM);
  // up: H = (x.w1^T * s) * SG, in-place over SGH, + absmax(H)
  gemm8p<1><<<gUp, 512, 0, stream>>>(qx, qw1, SGH, SGH, slots, 0, 1, slots + 4, DDIM, FDIM);
  quant_kernel<<<2048, 256, 0, stream>>>(SGH, qh, n4h, slots + 4);
  // down: out = (h.w2^T) * s
  gemm8p<2><<<gDn, 512, 0, stream>>>(qh, qw2, out, nullptr, slots, 4, 3, nullptr, FDIM, DDIM);
}

// Round 4
// 1050.986 us; speedup vs baseline: 1.5282x; 1.5282x over previous
//
#include <hip/hip_runtime.h>
#include <hip/hip_bf16.h>

typedef __attribute__((ext_vector_type(4))) int int4v;
typedef __attribute__((ext_vector_type(4))) float f32x4;

#define MFMA_I8(a, b, c) __builtin_amdgcn_mfma_i32_16x16x64_i8((a), (b), (c), 0, 0, 0)
#define GLDS16(g, l)                                                                        \
  __builtin_amdgcn_global_load_lds((const __attribute__((address_space(1))) void*)(g),      \
                                   (__attribute__((address_space(3))) void*)(l), 16, 0, 0)
#define SBAR() __builtin_amdgcn_s_barrier()
#define SCHED0() __builtin_amdgcn_sched_barrier(0)

static constexpr int NTOK = 4096;
static constexpr int DDIM = 4096;
static constexpr int FDIM = 11008;

// ---------------------------------------------------------------- utilities

__device__ __forceinline__ float wave_max64(float m) {
#pragma unroll
  for (int o = 32; o > 0; o >>= 1) m = fmaxf(m, __shfl_xor(m, o));
  return m;
}

__global__ void zero_slots(unsigned* s) {
  if (threadIdx.x < 16) s[threadIdx.x] = 0u;
}

__global__ void absmax_kernel(const float* __restrict__ p, int n4, unsigned* __restrict__ slot) {
  float m = 0.f;
  const int stride = gridDim.x * blockDim.x;
  for (int i = blockIdx.x * blockDim.x + threadIdx.x; i < n4; i += stride) {
    float4 v = reinterpret_cast<const float4*>(p)[i];
    m = fmaxf(fmaxf(fabsf(v.x), fabsf(v.y)), fmaxf(fmaxf(fabsf(v.z), fabsf(v.w)), m));
  }
  m = wave_max64(m);
  __shared__ float wm[4];
  const int lane = threadIdx.x & 63, w = threadIdx.x >> 6;
  if (lane == 0) wm[w] = m;
  __syncthreads();
  if (threadIdx.x == 0) {
    m = fmaxf(fmaxf(wm[0], wm[1]), fmaxf(wm[2], wm[3]));
    atomicMax(slot, __float_as_uint(m));
  }
}

// q = rint(t / s) as signed i8, 4 packed per u32 (|q| <= 127, exact)
__global__ void quant_kernel(const float* __restrict__ in, unsigned* __restrict__ out,
                             int n4, const unsigned* __restrict__ slot) {
  const float s = fmaxf(__uint_as_float(*slot), 1e-8f) / 127.0f;
  const int stride = gridDim.x * blockDim.x;
  for (int i = blockIdx.x * blockDim.x + threadIdx.x; i < n4; i += stride) {
    float4 v = reinterpret_cast<const float4*>(in)[i];
    const int q0 = (int)rintf(v.x / s), q1 = (int)rintf(v.y / s);
    const int q2 = (int)rintf(v.z / s), q3 = (int)rintf(v.w / s);
    out[i] = (unsigned)(q0 & 255) | ((unsigned)(q1 & 255) << 8) |
             ((unsigned)(q2 & 255) << 16) | ((unsigned)(q3 & 255) << 24);
  }
}

// ------------------------------------------------ 256x256 8-phase GEMM (i8)
// C[M][N] = scale * A[M][K] . B[N][K]^T, A/B int8. mfma_i32_16x16x64_i8,
// exact i32 accumulate (|acc| <= 127*127*11008 < 2^31).
// 8 waves (2Mx4N), per-wave C = 128x64. BK=128 i8 (128 B/row), double-buffered
// 128 KiB LDS: per buffer A[256][128B] @0, B[256][128B] @32768.
// XOR swizzle on 16B granules: phys = logical ^ (row & 7), applied on the
// global SOURCE address (linear LDS dest) and on ds_read (both-sides rule).
// Schedule (round-2 measured-best): per tile kt (buf b), stage per phase:
//   ph1: B-h0(kt+1)->bufn  ph2: B-h1(kt+1)->bufn
//   ph3: A-h0(kt+2)->buf b ph4: A-h1(kt+2)->buf b   (A region free after ph2)
// Boundary s_waitcnt vmcnt(4): drains tile kt's 8 loads, keeps newest 4.
// XCD chunking: column-major so each XCD re-reads few B panels.
// MODE 0: C = silu(v)  MODE 1: C = v * SG (in-place) + absmax->hslot
// MODE 2: C = v
template <int MODE>
__global__ __launch_bounds__(512, 2) void gemm8p(
    const signed char* __restrict__ Aq, const signed char* __restrict__ Bq,
    float* C, const float* SG, const unsigned* __restrict__ slots, int sA, int sB,
    unsigned* hslot, int K, int ldc) {
  __shared__ char lds[131072];  // 128 KiB

  const int t = threadIdx.x;
  const int l = t & 63;
  const int w = t >> 6;   // wave 0..7
  const int wm = w >> 2;  // 0..1
  const int wn = w & 3;   // 0..3

  // XCD-aware COLUMN-MAJOR chunking (nwg % 8 == 0 for all our grids)
  const int gx = gridDim.x;  // column tiles
  const int gy = gridDim.y;  // row tiles
  const int nwg = gx * gy;
  const int i0 = blockIdx.y * gx + blockIdx.x;
  const int cid = (i0 & 7) * (nwg >> 3) + (i0 >> 3);
  const int rowA0 = (cid % gy) << 8;  // C-row tile base
  const int colB0 = (cid / gy) << 8;  // C-col (B-row) base

  // staging: per-thread global BYTE offsets (one instr covers 64 rows)
  const int rl = t >> 3;               // local row 0..63
  const int c16 = (t & 7) ^ (rl & 7);  // pre-swizzled 16B granule
  const size_t aOff0 = (size_t)(rowA0 + rl) * K + c16 * 16;
  const size_t aOff1 = aOff0 + (size_t)64 * K;
  const size_t bOff0 = (size_t)(colB0 + rl) * K + c16 * 16;
  const size_t bOff1 = bOff0 + (size_t)64 * K;
  const size_t hstep = (size_t)128 * K;  // half-tile row step (bytes)
  const int stW = w * 1024;              // wave-uniform LDS byte offset

#define STAGE2(PTR, O0, O1, LB)             \
  do {                                      \
    GLDS16((PTR) + (O0), &lds[(LB) + stW]); \
    GLDS16((PTR) + (O1), &lds[(LB) + 8192 + stW]); \
  } while (0)

// swizzled LDS reads (ROW in 0..255, G = logical 16B granule 0..7)
#define LDA(BUF, ROW, G) \
  (*reinterpret_cast<const int4v*>(&lds[(BUF)*65536 + (ROW)*128 + (((G) ^ ((ROW)&7)) << 4)]))
#define LDB(BUF, ROW, G) \
  (*reinterpret_cast<const int4v*>(&lds[(BUF)*65536 + 32768 + (ROW)*128 + (((G) ^ ((ROW)&7)) << 4)]))

#define MFMA16(MH, NH, AF, BF)                                                  \
  do {                                                                          \
    _Pragma("unroll") for (int kk = 0; kk < 2; ++kk)                            \
    _Pragma("unroll") for (int m = 0; m < 4; ++m)                               \
    _Pragma("unroll") for (int n = 0; n < 2; ++n)                               \
      acc[(MH)*4 + m][(NH)*2 + n] =                                             \
          MFMA_I8(AF[kk][m], BF[kk][n], acc[(MH)*4 + m][(NH)*2 + n]);           \
  } while (0)

  int4v acc[8][4];
#pragma unroll
  for (int mi = 0; mi < 8; ++mi)
#pragma unroll
    for (int ni = 0; ni < 4; ++ni) acc[mi][ni] = (int4v){0, 0, 0, 0};

  const int NT = K >> 7;               // K / 128
  const int ar = wm * 128 + (l & 15);  // A row base (mh=0)
  const int br = wn * 64 + (l & 15);   // B row base (nh=0)
  const int cr = l >> 4;               // logical granule base (kk adds 4)

  // prologue: tile0 (A,B) -> buf0; tile1 A halves -> buf1 (12 loads)
  STAGE2(Aq, aOff0, aOff1, 0);
  STAGE2(Aq, aOff0 + hstep, aOff1 + hstep, 16384);
  STAGE2(Bq, bOff0, bOff1, 32768);
  STAGE2(Bq, bOff0 + hstep, bOff1 + hstep, 49152);
  STAGE2(Aq, aOff0 + 128, aOff1 + 128, 65536);
  STAGE2(Aq, aOff0 + hstep + 128, aOff1 + hstep + 128, 65536 + 16384);

  for (int kt = 0; kt < NT; ++kt) {
    const int b = kt & 1, bn = b ^ 1;
    const size_t kO = (size_t)(kt + 1) * 128;   // next tile byte col offset
    const size_t kO2 = (size_t)(kt + 2) * 128;  // tile+2 byte col offset

    // ---- tile boundary: tile kt fully landed (newest 4 stay in flight)
    SCHED0();
    if (kt + 1 < NT) {
      asm volatile("s_waitcnt vmcnt(4)" ::: "memory");
    } else {
      asm volatile("s_waitcnt vmcnt(0)" ::: "memory");
    }
    SBAR();
    SCHED0();

    int4v aH[2][4], aC[2][4], b0[2][2], b1[2][2];

    // ---- phase 1: read A(mh0)+B(nh0); stage (kt+1) B-h0 -> buf bn
#pragma unroll
    for (int kk = 0; kk < 2; ++kk)
#pragma unroll
      for (int m = 0; m < 4; ++m) aH[kk][m] = LDA(b, ar + m * 16, kk * 4 + cr);
#pragma unroll
    for (int kk = 0; kk < 2; ++kk)
#pragma unroll
      for (int n = 0; n < 2; ++n) b0[kk][n] = LDB(b, br + n * 16, kk * 4 + cr);
    if (kt + 1 < NT) STAGE2(Bq, bOff0 + kO, bOff1 + kO, bn * 65536 + 32768);
    SCHED0(); SBAR(); SCHED0();
    __builtin_amdgcn_s_setprio(1);
    MFMA16(0, 0, aH, b0);
    __builtin_amdgcn_s_setprio(0);
    SCHED0(); SBAR(); SCHED0();

    // ---- phase 2: read A(mh1); stage (kt+1) B-h1 -> buf bn
#pragma unroll
    for (int kk = 0; kk < 2; ++kk)
#pragma unroll
      for (int m = 0; m < 4; ++m) aC[kk][m] = LDA(b, ar + 64 + m * 16, kk * 4 + cr);
    if (kt + 1 < NT) STAGE2(Bq, bOff0 + hstep + kO, bOff1 + hstep + kO, bn * 65536 + 49152);
    SCHED0(); SBAR(); SCHED0();
    __builtin_amdgcn_s_setprio(1);
    MFMA16(1, 0, aC, b0);
    __builtin_amdgcn_s_setprio(0);
    SCHED0(); SBAR(); SCHED0();

    // ---- phase 3: read B(nh1); stage (kt+2) A-h0 -> buf b (A free after ph2)
#pragma unroll
    for (int kk = 0; kk < 2; ++kk)
#pragma unroll
      for (int n = 0; n < 2; ++n) b1[kk][n] = LDB(b, br + 32 + n * 16, kk * 4 + cr);
    if (kt + 2 < NT) STAGE2(Aq, aOff0 + kO2, aOff1 + kO2, b * 65536);
    SCHED0(); SBAR(); SCHED0();
    __builtin_amdgcn_s_setprio(1);
    MFMA16(1, 1, aC, b1);
    __builtin_amdgcn_s_setprio(0);
    SCHED0(); SBAR(); SCHED0();

    // ---- phase 4: stage (kt+2) A-h1 -> buf b
    if (kt + 2 < NT) STAGE2(Aq, aOff0 + hstep + kO2, aOff1 + hstep + kO2, b * 65536 + 16384);
    SCHED0(); SBAR(); SCHED0();
    __builtin_amdgcn_s_setprio(1);
    MFMA16(0, 1, aH, b1);
    __builtin_amdgcn_s_setprio(0);
    SCHED0(); SBAR(); SCHED0();
  }

  // ------------------------------------------------------------- epilogue
  const float sa = fmaxf(__uint_as_float(slots[sA]), 1e-8f) / 127.0f;
  const float sb = fmaxf(__uint_as_float(slots[sB]), 1e-8f) / 127.0f;
  const float s = sa * sb;
  const int crow0 = rowA0 + wm * 128 + ((l >> 4) << 2);
  const int ccol0 = colB0 + wn * 64 + (l & 15);
  float hmax = 0.f;
#pragma unroll
  for (int mi = 0; mi < 8; ++mi)
#pragma unroll
    for (int ni = 0; ni < 4; ++ni)
#pragma unroll
      for (int j = 0; j < 4; ++j) {
        const int row = crow0 + (mi >> 2) * 64 + (mi & 3) * 16 + j;
        const int col = ccol0 + (ni >> 1) * 32 + (ni & 1) * 16;
        const float v = (float)acc[mi][ni][j] * s;
        if constexpr (MODE == 0) {
          C[(size_t)row * ldc + col] = v / (1.f + expf(-v));  // silu
        } else if constexpr (MODE == 1) {
          const float h = v * SG[(size_t)row * ldc + col];
          C[(size_t)row * ldc + col] = h;
          hmax = fmaxf(hmax, fabsf(h));
        } else {
          C[(size_t)row * ldc + col] = v;
        }
      }
  if constexpr (MODE == 1) {
    hmax = wave_max64(hmax);
    if (l == 0) atomicMax(hslot, __float_as_uint(hmax));
  }
#undef STAGE2
#undef LDA
#undef LDB
#undef MFMA16
}

// ------------------------------------------------------------------- launch

extern "C" void kernel_launch(void* const* d_in, const int* in_sizes, int n_in,
                              void* d_out, int out_size, void* d_ws, size_t ws_size,
                              hipStream_t stream) {
  const float* x = (const float*)d_in[0];
  const float* w1 = (const float*)d_in[1];
  const float* w3 = (const float*)d_in[2];
  const float* w2 = (const float*)d_in[3];
  float* out = (float*)d_out;
  char* ws = (char*)d_ws;

  unsigned* slots = (unsigned*)ws;  // [0]=x [1]=w1 [2]=w3 [3]=w2 [4]=h absmax
  size_t off = 256;
  signed char* qx = (signed char*)(ws + off);
  off += (size_t)NTOK * DDIM;
  signed char* qw3 = (signed char*)(ws + off);
  off += (size_t)FDIM * DDIM;
  signed char* qw1 = (signed char*)(ws + off);
  off += (size_t)FDIM * DDIM;
  signed char* qw2 = (signed char*)(ws + off);
  off += (size_t)FDIM * DDIM;
  float* SGH = (float*)(ws + off);  // silu(gate), overwritten in-place by h
  off += (size_t)NTOK * FDIM * 4;
  signed char* qh = (signed char*)(ws + off);
  off += (size_t)NTOK * FDIM;  // ~385 MB total

  const int n4x = NTOK * DDIM / 4;
  const int n4w = FDIM * DDIM / 4;
  const int n4h = NTOK * FDIM / 4;

  zero_slots<<<1, 64, 0, stream>>>(slots);
  absmax_kernel<<<2048, 256, 0, stream>>>(x, n4x, slots + 0);
  absmax_kernel<<<2048, 256, 0, stream>>>(w1, n4w, slots + 1);
  absmax_kernel<<<2048, 256, 0, stream>>>(w3, n4w, slots + 2);
  absmax_kernel<<<2048, 256, 0, stream>>>(w2, n4w, slots + 3);

  quant_kernel<<<2048, 256, 0, stream>>>(x, (unsigned*)qx, n4x, slots + 0);
  quant_kernel<<<2048, 256, 0, stream>>>(w1, (unsigned*)qw1, n4w, slots + 1);
  quant_kernel<<<2048, 256, 0, stream>>>(w3, (unsigned*)qw3, n4w, slots + 2);
  quant_kernel<<<2048, 256, 0, stream>>>(w2, (unsigned*)qw2, n4w, slots + 3);

  const dim3 gUp(FDIM / 256, NTOK / 256);  // 43 x 16 = 688 wgs
  const dim3 gDn(DDIM / 256, NTOK / 256);  // 16 x 16 = 256 wgs
  // gate: SG = silu(x.w3^T * s)
  gemm8p<0><<<gUp, 512, 0, stream>>>(qx, qw3, SGH, nullptr, slots, 0, 2, nullptr, DDIM, FDIM);
  // up: H = (x.w1^T * s) * SG, in-place over SGH, + absmax(H)
  gemm8p<1><<<gUp, 512, 0, stream>>>(qx, qw1, SGH, SGH, slots, 0, 1, slots + 4, DDIM, FDIM);
  quant_kernel<<<2048, 256, 0, stream>>>(SGH, (unsigned*)qh, n4h, slots + 4);
  // down: out = (h.w2^T) * s
  gemm8p<2><<<gDn, 512, 0, stream>>>(qh, qw2, out, nullptr, slots, 4, 3, nullptr, FDIM, DDIM);
}